// Round 4
// baseline (1039.896 us; speedup 1.0000x reference)
//
#include <hip/hip_runtime.h>
#include <math.h>

// ---------------- dims ----------------
#define BB 64
#define H1 116
#define W1 212
#define C1c 10
#define OH1 112
#define OW1 208
#define PH1 56
#define PW1 104
#define C2c 20
#define OH2 52
#define OW2 100
#define PH2 26
#define PW2 50
#define FLAT 26000
#define HID 512
#define NCLS 10
#define EPSV 1e-5
#define NB1 1456
#define NB2 325
#define COG 5   // conv2 output channels per thread (grid.y = C2c/COG = 4)

// ============================================================
// init: bias-init FC accumulators
// ============================================================
__global__ __launch_bounds__(256) void k_init(
                       float* fc1r, float* fc1i, float* fc2r, float* fc2i,
                       const float* __restrict__ f1br, const float* __restrict__ f1bi,
                       const float* __restrict__ f2br, const float* __restrict__ f2bi) {
    int idx = blockIdx.x * 256 + threadIdx.x;
    if (idx < BB * HID) {
        int n = idx % HID;
        fc1r[idx] = f1br[n]; fc1i[idx] = f1bi[n];
        fc2r[idx] = f2br[n]; fc2i[idx] = f2bi[n];
    }
}

// ============================================================
// conv1 + stats partials (no store; conv1 recomputed in apply pass)
// grid (1456, 10), block 256.  per-c pixels/4 = 64*112*52 = 372736
// ============================================================
__global__ __launch_bounds__(256) void k_conv1_stats(
                              const float* __restrict__ xr, const float* __restrict__ xi,
                              const float* __restrict__ w1r, const float* __restrict__ w1i,
                              const float* __restrict__ b1r, const float* __restrict__ b1i,
                              double* __restrict__ part) {
    __shared__ float swr[25], swi[25];
    __shared__ double red[4][5];
    int tid = threadIdx.x;
    int c = blockIdx.y;
    if (tid < 25) { swr[tid] = w1r[c * 25 + tid]; swi[tid] = w1i[c * 25 + tid]; }
    __syncthreads();
    int idx = blockIdx.x * 256 + tid;
    int wg = idx % 52;
    int h  = (idx / 52) % OH1;
    int b  = idx / (52 * OH1);
    int w0 = wg * 4;
    float br = b1r[c], bi = b1i[c];
    float yr[4], yi[4];
#pragma unroll
    for (int j = 0; j < 4; j++) { yr[j] = br; yi[j] = bi; }
    const float* xrb = xr + b * (H1 * W1);
    const float* xib = xi + b * (H1 * W1);
#pragma unroll
    for (int kh = 0; kh < 5; kh++) {
        float ar[8], ai[8];
        const float* pr = xrb + (h + kh) * W1 + w0;
        const float* pi = xib + (h + kh) * W1 + w0;
        *(float4*)&ar[0] = *(const float4*)pr;
        *(float4*)&ar[4] = *(const float4*)(pr + 4);
        *(float4*)&ai[0] = *(const float4*)pi;
        *(float4*)&ai[4] = *(const float4*)(pi + 4);
#pragma unroll
        for (int kw = 0; kw < 5; kw++) {
            float wrv = swr[kh * 5 + kw], wiv = swi[kh * 5 + kw];
#pragma unroll
            for (int j = 0; j < 4; j++) {
                float vr = ar[kw + j], vi = ai[kw + j];
                yr[j] += vr * wrv - vi * wiv;
                yi[j] += vr * wiv + vi * wrv;
            }
        }
    }
    double v[5] = {0, 0, 0, 0, 0};
#pragma unroll
    for (int j = 0; j < 4; j++) {
        double r = yr[j], i = yi[j];
        v[0] += r; v[1] += i; v[2] += r * r; v[3] += i * i; v[4] += r * i;
    }
#pragma unroll
    for (int m = 32; m >= 1; m >>= 1) {
#pragma unroll
        for (int q = 0; q < 5; q++) v[q] += __shfl_xor(v[q], m, 64);
    }
    if ((tid & 63) == 0) {
#pragma unroll
        for (int q = 0; q < 5; q++) red[tid >> 6][q] = v[q];
    }
    __syncthreads();
    if (tid == 0) {
#pragma unroll
        for (int q = 0; q < 5; q++)
            part[(c * 5 + q) * NB1 + blockIdx.x] = red[0][q] + red[1][q] + red[2][q] + red[3][q];
    }
}

// ============================================================
// reduce per-block partials -> sums[c*5+q]. grid C blocks, 320 thr
// ============================================================
__global__ __launch_bounds__(320) void k_part_reduce(
                              const double* __restrict__ part, int NB,
                              double* __restrict__ sums) {
    int c = blockIdx.x;
    int q = threadIdx.x >> 6;
    int lane = threadIdx.x & 63;
    double s = 0.0;
    for (int b = lane; b < NB; b += 64) s += part[(c * 5 + q) * NB + b];
#pragma unroll
    for (int m = 32; m >= 1; m >>= 1) s += __shfl_xor(s, m, 64);
    if (lane == 0) sums[c * 5 + q] = s;
}

// ============================================================
// BN coefficients from double sums (conv layers). 1 block.
// ============================================================
__global__ __launch_bounds__(64) void k_bn_coef(
                          const double* __restrict__ sums, int C, double invN,
                          const float* __restrict__ grr, const float* __restrict__ gri,
                          const float* __restrict__ gii,
                          const float* __restrict__ ber, const float* __restrict__ bei,
                          float* __restrict__ coef) {
    int c = threadIdx.x;
    if (c >= C) return;
    double sr = sums[c * 5 + 0], si = sums[c * 5 + 1];
    double srr = sums[c * 5 + 2], sii = sums[c * 5 + 3], sri = sums[c * 5 + 4];
    double mr = sr * invN, mi = si * invN;
    double Vrr = srr * invN - mr * mr + EPSV;
    double Vii = sii * invN - mi * mi + EPSV;
    double Vri = sri * invN - mr * mi;
    double s = sqrt(Vrr * Vii - Vri * Vri);
    double t = sqrt(Vrr + Vii + 2.0 * s);
    double inv = 1.0 / (s * t);
    double Rrr = (Vii + s) * inv, Rii = (Vrr + s) * inv, Rri = -Vri * inv;
    double Grr = grr[c], Gri = gri[c], Gii = gii[c];
    double Arr = Grr * Rrr + Gri * Rri, Ari = Grr * Rri + Gri * Rii;
    double Air = Gri * Rrr + Gii * Rri, Aii = Gri * Rri + Gii * Rii;
    coef[c * 6 + 0] = (float)Arr;
    coef[c * 6 + 1] = (float)Ari;
    coef[c * 6 + 2] = (float)Air;
    coef[c * 6 + 3] = (float)Aii;
    coef[c * 6 + 4] = (float)((double)ber[c] - (Arr * mr + Ari * mi));
    coef[c * 6 + 5] = (float)((double)bei[c] - (Air * mr + Aii * mi));
}

// ============================================================
// conv1 recompute + BN affine + relu + mag-pool -> P1 [b][c][56][104]
// grid (728, 10)
// ============================================================
__global__ __launch_bounds__(256) void k_conv1_apply_pool(
                                   const float* __restrict__ xr, const float* __restrict__ xi,
                                   const float* __restrict__ w1r, const float* __restrict__ w1i,
                                   const float* __restrict__ b1r, const float* __restrict__ b1i,
                                   const float* __restrict__ coef,
                                   float* __restrict__ P1r, float* __restrict__ P1i) {
    __shared__ float swr[25], swi[25];
    int tid = threadIdx.x;
    int c = blockIdx.y;
    if (tid < 25) { swr[tid] = w1r[c * 25 + tid]; swi[tid] = w1i[c * 25 + tid]; }
    __syncthreads();
    int idx = blockIdx.x * 256 + tid;
    int pwg = idx % 52;
    int ph  = (idx / 52) % PH1;
    int b   = idx / (52 * PH1);
    int h0 = 2 * ph, w0 = 4 * pwg;
    float br = b1r[c], bi = b1i[c];
    float yr[2][4], yi[2][4];
#pragma unroll
    for (int oi = 0; oi < 2; oi++)
#pragma unroll
        for (int j = 0; j < 4; j++) { yr[oi][j] = br; yi[oi][j] = bi; }
    const float* xrb = xr + b * (H1 * W1);
    const float* xib = xi + b * (H1 * W1);
#pragma unroll
    for (int r = 0; r < 6; r++) {
        float ar[8], ai[8];
        const float* pr = xrb + (h0 + r) * W1 + w0;
        const float* pi = xib + (h0 + r) * W1 + w0;
        *(float4*)&ar[0] = *(const float4*)pr;
        *(float4*)&ar[4] = *(const float4*)(pr + 4);
        *(float4*)&ai[0] = *(const float4*)pi;
        *(float4*)&ai[4] = *(const float4*)(pi + 4);
#pragma unroll
        for (int oi = 0; oi < 2; oi++) {
            int kh = r - oi;
            if (kh >= 0 && kh < 5) {
#pragma unroll
                for (int kw = 0; kw < 5; kw++) {
                    float wrv = swr[kh * 5 + kw], wiv = swi[kh * 5 + kw];
#pragma unroll
                    for (int j = 0; j < 4; j++) {
                        float vr = ar[kw + j], vi = ai[kw + j];
                        yr[oi][j] += vr * wrv - vi * wiv;
                        yi[oi][j] += vr * wiv + vi * wrv;
                    }
                }
            }
        }
    }
    float Arr = coef[c * 6 + 0], Ari = coef[c * 6 + 1];
    float Air = coef[c * 6 + 2], Aii = coef[c * 6 + 3];
    float oR = coef[c * 6 + 4], oI = coef[c * 6 + 5];
    float bm0 = -1.f, br0 = 0.f, bi0 = 0.f;
    float bm1 = -1.f, br1 = 0.f, bi1 = 0.f;
#pragma unroll
    for (int oi = 0; oi < 2; oi++) {
#pragma unroll
        for (int j = 0; j < 4; j++) {
            float rr = fmaxf(Arr * yr[oi][j] + Ari * yi[oi][j] + oR, 0.f);
            float ii = fmaxf(Air * yr[oi][j] + Aii * yi[oi][j] + oI, 0.f);
            float m = rr * rr + ii * ii;
            if (j < 2) { if (m > bm0) { bm0 = m; br0 = rr; bi0 = ii; } }
            else       { if (m > bm1) { bm1 = m; br1 = rr; bi1 = ii; } }
        }
    }
    int pbase = ((b * C1c + c) * PH1 + ph) * PW1 + 2 * pwg;
    *(float2*)&P1r[pbase] = make_float2(br0, br1);
    *(float2*)&P1i[pbase] = make_float2(bi0, bi1);
}

// ============================================================
// conv2: P1 -> buf2 [b][c][52][100] (stored) + stats partials
// grid (325, 4): each thread computes COG=5 output channels for
// 4 output pixels -> input loads amortized 5x (FETCH 404->~130 MB).
// ============================================================
__global__ __launch_bounds__(256) void k_conv2_stats(
                              const float* __restrict__ P1r, const float* __restrict__ P1i,
                              const float* __restrict__ w2r, const float* __restrict__ w2i,
                              const float* __restrict__ b2r, const float* __restrict__ b2i,
                              float* __restrict__ buf2r, float* __restrict__ buf2i,
                              double* __restrict__ part) {
    __shared__ float swr[COG][250], swi[COG][250];
    __shared__ double red[4][5];
    int tid = threadIdx.x;
    int cg = blockIdx.y;                 // channel group: couts cg*COG .. cg*COG+4
    if (tid < 250) {
#pragma unroll
        for (int g = 0; g < COG; g++) {
            swr[g][tid] = w2r[(cg * COG + g) * 250 + tid];
            swi[g][tid] = w2i[(cg * COG + g) * 250 + tid];
        }
    }
    __syncthreads();
    int idx = blockIdx.x * 256 + tid;
    int wg = idx % 25;
    int h  = (idx / 25) % OH2;
    int b  = idx / (25 * OH2);
    int w0 = 4 * wg;
    float yr[COG][4], yi[COG][4];
#pragma unroll
    for (int g = 0; g < COG; g++) {
        float br = b2r[cg * COG + g], bi = b2i[cg * COG + g];
#pragma unroll
        for (int j = 0; j < 4; j++) { yr[g][j] = br; yi[g][j] = bi; }
    }
    for (int cin = 0; cin < C1c; cin++) {
        const float* pr = P1r + ((b * C1c + cin) * PH1 + h) * PW1 + w0;
        const float* pi = P1i + ((b * C1c + cin) * PH1 + h) * PW1 + w0;
#pragma unroll
        for (int kh = 0; kh < 5; kh++) {
            float ar[8], ai[8];
            *(float4*)&ar[0] = *(const float4*)(pr + kh * PW1);
            *(float4*)&ar[4] = *(const float4*)(pr + kh * PW1 + 4);
            *(float4*)&ai[0] = *(const float4*)(pi + kh * PW1);
            *(float4*)&ai[4] = *(const float4*)(pi + kh * PW1 + 4);
#pragma unroll
            for (int g = 0; g < COG; g++) {
                const float* wr = &swr[g][cin * 25 + kh * 5];
                const float* wi = &swi[g][cin * 25 + kh * 5];
#pragma unroll
                for (int kw = 0; kw < 5; kw++) {
                    float wrv = wr[kw], wiv = wi[kw];
#pragma unroll
                    for (int j = 0; j < 4; j++) {
                        float vr = ar[kw + j], vi = ai[kw + j];
                        yr[g][j] += vr * wrv - vi * wiv;
                        yi[g][j] += vr * wiv + vi * wrv;
                    }
                }
            }
        }
    }
#pragma unroll
    for (int g = 0; g < COG; g++) {
        int ob = ((b * C2c + cg * COG + g) * OH2 + h) * OW2 + w0;
        *(float4*)&buf2r[ob] = make_float4(yr[g][0], yr[g][1], yr[g][2], yr[g][3]);
        *(float4*)&buf2i[ob] = make_float4(yi[g][0], yi[g][1], yi[g][2], yi[g][3]);
    }
    // stats: sequential per channel to cap register pressure
    for (int g = 0; g < COG; g++) {
        double v[5] = {0, 0, 0, 0, 0};
#pragma unroll
        for (int j = 0; j < 4; j++) {
            double r = yr[g][j], i = yi[g][j];
            v[0] += r; v[1] += i; v[2] += r * r; v[3] += i * i; v[4] += r * i;
        }
#pragma unroll
        for (int m = 32; m >= 1; m >>= 1) {
#pragma unroll
            for (int q = 0; q < 5; q++) v[q] += __shfl_xor(v[q], m, 64);
        }
        if ((tid & 63) == 0) {
#pragma unroll
            for (int q = 0; q < 5; q++) red[tid >> 6][q] = v[q];
        }
        __syncthreads();
        if (tid == 0) {
            int c = cg * COG + g;
#pragma unroll
            for (int q = 0; q < 5; q++)
                part[(c * 5 + q) * NB2 + blockIdx.x] = red[0][q] + red[1][q] + red[2][q] + red[3][q];
        }
        __syncthreads();
    }
}

// ============================================================
// BN2 affine + relu + mag-pool, write transposed P2T [k=26000][b=64]
// ============================================================
__global__ __launch_bounds__(256) void k_bn2_pool(
                           const float* __restrict__ buf2r, const float* __restrict__ buf2i,
                           const float* __restrict__ coef,
                           float* __restrict__ P2Tr, float* __restrict__ P2Ti) {
    int idx = blockIdx.x * 256 + threadIdx.x;
    int pw = idx % PW2;
    int ph = (idx / PW2) % PH2;
    int c  = (idx / (PW2 * PH2)) % C2c;
    int b  = idx / (PW2 * PH2 * C2c);
    float Arr = coef[c * 6 + 0], Ari = coef[c * 6 + 1];
    float Air = coef[c * 6 + 2], Aii = coef[c * 6 + 3];
    float oR = coef[c * 6 + 4], oI = coef[c * 6 + 5];
    int ib = ((b * C2c + c) * OH2 + 2 * ph) * OW2 + 2 * pw;
    float rv[4], iv[4];
    rv[0] = buf2r[ib];           iv[0] = buf2i[ib];
    rv[1] = buf2r[ib + 1];       iv[1] = buf2i[ib + 1];
    rv[2] = buf2r[ib + OW2];     iv[2] = buf2i[ib + OW2];
    rv[3] = buf2r[ib + OW2 + 1]; iv[3] = buf2i[ib + OW2 + 1];
    float bm = -1.f, brv = 0.f, biv = 0.f;
#pragma unroll
    for (int q = 0; q < 4; q++) {
        float rr = fmaxf(Arr * rv[q] + Ari * iv[q] + oR, 0.f);
        float ii = fmaxf(Air * rv[q] + Aii * iv[q] + oI, 0.f);
        float m = rr * rr + ii * ii;
        if (m > bm) { bm = m; brv = rr; biv = ii; }
    }
    int k = (c * PH2 + ph) * PW2 + pw;
    P2Tr[k * BB + b] = brv;
    P2Ti[k * BB + b] = biv;
}

// ============================================================
// complex GEMM: out[64][512] += XT[k][64] (x) W[n][k]
// ============================================================
#define GKC 32
__global__ __launch_bounds__(256) void k_gemm_cplx(
                            const float* __restrict__ XTr, const float* __restrict__ XTi,
                            const float* __restrict__ Wr, const float* __restrict__ Wi,
                            float* __restrict__ outR, float* __restrict__ outI,
                            int K, int nStages, int nSplit) {
    __shared__ float lxr[GKC][64], lxi[GKC][64];
    __shared__ float lwr[GKC][68], lwi[GKC][68];
    int tid = threadIdx.x;
    int n0 = blockIdx.x * 64;
    int split = blockIdx.y;
    int bq = tid & 15, nq = tid >> 4;
    int nl = tid & 63, kg = tid >> 6;
    float accR[4][4] = {}, accI[4][4] = {};
    for (int st = split; st < nStages; st += nSplit) {
        int k0 = st * GKC;
        __syncthreads();
#pragma unroll
        for (int u = 0; u < 2; u++) {
            int p = u * 1024 + tid * 4;
            int g = k0 * 64 + p;
            float4 vr = make_float4(0.f, 0.f, 0.f, 0.f), vi = vr;
            if (g < K * 64) {
                vr = *(const float4*)(XTr + g);
                vi = *(const float4*)(XTi + g);
            }
            *(float4*)&((float*)lxr)[p] = vr;
            *(float4*)&((float*)lxi)[p] = vi;
        }
#pragma unroll
        for (int u = 0; u < 2; u++) {
            int koff = kg * 8 + u * 4;
            int k = k0 + koff;
            float4 vr = make_float4(0.f, 0.f, 0.f, 0.f), vi = vr;
            if (k < K) {
                vr = *(const float4*)(Wr + (size_t)(n0 + nl) * K + k);
                vi = *(const float4*)(Wi + (size_t)(n0 + nl) * K + k);
            }
            lwr[koff + 0][nl] = vr.x; lwr[koff + 1][nl] = vr.y;
            lwr[koff + 2][nl] = vr.z; lwr[koff + 3][nl] = vr.w;
            lwi[koff + 0][nl] = vi.x; lwi[koff + 1][nl] = vi.y;
            lwi[koff + 2][nl] = vi.z; lwi[koff + 3][nl] = vi.w;
        }
        __syncthreads();
#pragma unroll 4
        for (int kk = 0; kk < GKC; kk++) {
            float4 xr4 = *(const float4*)&lxr[kk][bq * 4];
            float4 xi4 = *(const float4*)&lxi[kk][bq * 4];
            float4 wr4 = *(const float4*)&lwr[kk][nq * 4];
            float4 wi4 = *(const float4*)&lwi[kk][nq * 4];
            float xra[4] = {xr4.x, xr4.y, xr4.z, xr4.w};
            float xia[4] = {xi4.x, xi4.y, xi4.z, xi4.w};
            float wra[4] = {wr4.x, wr4.y, wr4.z, wr4.w};
            float wia[4] = {wi4.x, wi4.y, wi4.z, wi4.w};
#pragma unroll
            for (int i = 0; i < 4; i++)
#pragma unroll
                for (int j = 0; j < 4; j++) {
                    accR[i][j] += xra[i] * wra[j] - xia[i] * wia[j];
                    accI[i][j] += xra[i] * wia[j] + xia[i] * wra[j];
                }
        }
    }
#pragma unroll
    for (int i = 0; i < 4; i++)
#pragma unroll
        for (int j = 0; j < 4; j++) {
            int b = bq * 4 + i;
            int n = n0 + nq * 4 + j;
            unsafeAtomicAdd(&outR[b * HID + n], accR[i][j]);
            unsafeAtomicAdd(&outI[b * HID + n], accI[i][j]);
        }
}

// ============================================================
// FC BN coef (batch axis only, N=64), C features
// ============================================================
__global__ __launch_bounds__(256) void k_bnfc_coef(
                            const float* __restrict__ inr, const float* __restrict__ ini, int C,
                            const float* __restrict__ grr, const float* __restrict__ gri,
                            const float* __restrict__ gii,
                            const float* __restrict__ ber, const float* __restrict__ bei,
                            float* __restrict__ coef) {
    int f = blockIdx.x * 256 + threadIdx.x;
    if (f >= C) return;
    double sr = 0, si = 0, srr = 0, sii = 0, sri = 0;
    for (int b = 0; b < BB; b++) {
        double r = inr[b * C + f], i = ini[b * C + f];
        sr += r; si += i; srr += r * r; sii += i * i; sri += r * i;
    }
    double invN = 1.0 / BB;
    double mr = sr * invN, mi = si * invN;
    double Vrr = srr * invN - mr * mr + EPSV;
    double Vii = sii * invN - mi * mi + EPSV;
    double Vri = sri * invN - mr * mi;
    double s = sqrt(Vrr * Vii - Vri * Vri);
    double t = sqrt(Vrr + Vii + 2.0 * s);
    double inv = 1.0 / (s * t);
    double Rrr = (Vii + s) * inv, Rii = (Vrr + s) * inv, Rri = -Vri * inv;
    double Grr = grr[f], Gri = gri[f], Gii = gii[f];
    double Arr = Grr * Rrr + Gri * Rri, Ari = Grr * Rri + Gri * Rii;
    double Air = Gri * Rrr + Gii * Rri, Aii = Gri * Rri + Gii * Rii;
    coef[f * 6 + 0] = (float)Arr;
    coef[f * 6 + 1] = (float)Ari;
    coef[f * 6 + 2] = (float)Air;
    coef[f * 6 + 3] = (float)Aii;
    coef[f * 6 + 4] = (float)((double)ber[f] - (Arr * mr + Ari * mi));
    coef[f * 6 + 5] = (float)((double)bei[f] - (Air * mr + Aii * mi));
}

// ============================================================
// FC BN apply + relu; optional transposed output [f][64]
// ============================================================
__global__ __launch_bounds__(256) void k_bnfc_apply(
                             const float* __restrict__ inr, const float* __restrict__ ini,
                             const float* __restrict__ coef,
                             float* __restrict__ outr, float* __restrict__ outi,
                             int C, int transposeOut) {
    int idx = blockIdx.x * 256 + threadIdx.x;
    if (idx >= BB * C) return;
    int f = idx % C;
    int b = idx / C;
    float r = inr[idx], i = ini[idx];
    float rr = fmaxf(coef[f * 6 + 0] * r + coef[f * 6 + 1] * i + coef[f * 6 + 4], 0.f);
    float ii = fmaxf(coef[f * 6 + 2] * r + coef[f * 6 + 3] * i + coef[f * 6 + 5], 0.f);
    if (transposeOut) { outr[f * BB + b] = rr; outi[f * BB + b] = ii; }
    else              { outr[idx] = rr;        outi[idx] = ii; }
}

// ============================================================
// classifier (512->10 complex) + |z|^2 + log_softmax
// ============================================================
__global__ __launch_bounds__(64) void k_classifier(
                             const float* __restrict__ xr, const float* __restrict__ xi,
                             const float* __restrict__ cwr, const float* __restrict__ cwi,
                             const float* __restrict__ cbr, const float* __restrict__ cbi,
                             float* __restrict__ out) {
    int b = blockIdx.x;
    int lane = threadIdx.x;
    __shared__ float z[NCLS];
    for (int cls = 0; cls < NCLS; cls++) {
        float ar = 0.f, ai = 0.f;
#pragma unroll
        for (int j = 0; j < 8; j++) {
            int k = j * 64 + lane;
            float xrv = xr[b * HID + k], xiv = xi[b * HID + k];
            float wr = cwr[cls * HID + k], wi = cwi[cls * HID + k];
            ar += xrv * wr - xiv * wi;
            ai += xrv * wi + xiv * wr;
        }
#pragma unroll
        for (int m = 32; m >= 1; m >>= 1) {
            ar += __shfl_xor(ar, m, 64);
            ai += __shfl_xor(ai, m, 64);
        }
        if (lane == 0) {
            float hr = ar + cbr[cls], hi = ai + cbi[cls];
            z[cls] = hr * hr + hi * hi;
        }
    }
    __syncthreads();
    if (lane == 0) {
        float mx = z[0];
#pragma unroll
        for (int c = 1; c < NCLS; c++) mx = fmaxf(mx, z[c]);
        float s = 0.f;
#pragma unroll
        for (int c = 0; c < NCLS; c++) s += expf(z[c] - mx);
        float ls = logf(s);
#pragma unroll
        for (int c = 0; c < NCLS; c++) out[b * NCLS + c] = z[c] - mx - ls;
    }
}

// ============================================================
extern "C" void kernel_launch(void* const* d_in, const int* in_sizes, int n_in,
                              void* d_out, int out_size, void* d_ws, size_t ws_size,
                              hipStream_t stream) {
    const float* x_re = (const float*)d_in[0];
    const float* x_im = (const float*)d_in[1];
    const float* w1r = (const float*)d_in[2];
    const float* w1i = (const float*)d_in[3];
    const float* b1r = (const float*)d_in[4];
    const float* b1i = (const float*)d_in[5];
    const float* g1rr = (const float*)d_in[6];
    const float* g1ri = (const float*)d_in[7];
    const float* g1ii = (const float*)d_in[8];
    const float* be1r = (const float*)d_in[9];
    const float* be1i = (const float*)d_in[10];
    const float* w2r = (const float*)d_in[11];
    const float* w2i = (const float*)d_in[12];
    const float* b2r = (const float*)d_in[13];
    const float* b2i = (const float*)d_in[14];
    const float* g2rr = (const float*)d_in[15];
    const float* g2ri = (const float*)d_in[16];
    const float* g2ii = (const float*)d_in[17];
    const float* be2r = (const float*)d_in[18];
    const float* be2i = (const float*)d_in[19];
    const float* f1wr = (const float*)d_in[20];
    const float* f1wi = (const float*)d_in[21];
    const float* f1br = (const float*)d_in[22];
    const float* f1bi = (const float*)d_in[23];
    const float* g3rr = (const float*)d_in[24];
    const float* g3ri = (const float*)d_in[25];
    const float* g3ii = (const float*)d_in[26];
    const float* be3r = (const float*)d_in[27];
    const float* be3i = (const float*)d_in[28];
    const float* f2wr = (const float*)d_in[29];
    const float* f2wi = (const float*)d_in[30];
    const float* f2br = (const float*)d_in[31];
    const float* f2bi = (const float*)d_in[32];
    const float* g4rr = (const float*)d_in[33];
    const float* g4ri = (const float*)d_in[34];
    const float* g4ii = (const float*)d_in[35];
    const float* be4r = (const float*)d_in[36];
    const float* be4i = (const float*)d_in[37];
    const float* cwr = (const float*)d_in[38];
    const float* cwi = (const float*)d_in[39];
    const float* cbr = (const float*)d_in[40];
    const float* cbi = (const float*)d_in[41];
    float* out = (float*)d_out;

    char* ws = (char*)d_ws;
    size_t off = 0;
    auto alloc = [&](size_t nbytes) -> void* {
        off = (off + 255) & ~(size_t)255;
        void* p = ws + off;
        off += nbytes;
        return p;
    };
    float* P1r   = (float*)alloc((size_t)BB * C1c * PH1 * PW1 * 4);
    float* P1i   = (float*)alloc((size_t)BB * C1c * PH1 * PW1 * 4);
    float* buf2r = (float*)alloc((size_t)BB * C2c * OH2 * OW2 * 4);
    float* buf2i = (float*)alloc((size_t)BB * C2c * OH2 * OW2 * 4);
    float* P2Tr  = (float*)alloc((size_t)FLAT * BB * 4);
    float* P2Ti  = (float*)alloc((size_t)FLAT * BB * 4);
    float* fc1r  = (float*)alloc((size_t)BB * HID * 4);
    float* fc1i  = (float*)alloc((size_t)BB * HID * 4);
    float* fc1aTr = (float*)alloc((size_t)HID * BB * 4);
    float* fc1aTi = (float*)alloc((size_t)HID * BB * 4);
    float* fc2r  = (float*)alloc((size_t)BB * HID * 4);
    float* fc2i  = (float*)alloc((size_t)BB * HID * 4);
    float* fc2ar = (float*)alloc((size_t)BB * HID * 4);
    float* fc2ai = (float*)alloc((size_t)BB * HID * 4);
    double* part1 = (double*)alloc((size_t)C1c * 5 * NB1 * 8);
    double* part2 = (double*)alloc((size_t)C2c * 5 * NB2 * 8);
    double* sums1 = (double*)alloc(C1c * 5 * 8);
    double* sums2 = (double*)alloc(C2c * 5 * 8);
    float* coef1 = (float*)alloc(C1c * 6 * 4);
    float* coef2 = (float*)alloc(C2c * 6 * 4);
    float* coefF1 = (float*)alloc(HID * 6 * 4);
    float* coefF2 = (float*)alloc(HID * 6 * 4);

    // 0) init
    k_init<<<128, 256, 0, stream>>>(fc1r, fc1i, fc2r, fc2i, f1br, f1bi, f2br, f2bi);
    // 1) conv1 stats partials
    k_conv1_stats<<<dim3(NB1, C1c), 256, 0, stream>>>(x_re, x_im, w1r, w1i, b1r, b1i, part1);
    k_part_reduce<<<C1c, 320, 0, stream>>>(part1, NB1, sums1);
    // 2) BN1 coefs
    k_bn_coef<<<1, 64, 0, stream>>>(sums1, C1c, 1.0 / ((double)BB * OH1 * OW1),
                                    g1rr, g1ri, g1ii, be1r, be1i, coef1);
    // 3) conv1 + BN + relu + pool -> P1
    k_conv1_apply_pool<<<dim3(728, C1c), 256, 0, stream>>>(x_re, x_im, w1r, w1i, b1r, b1i,
                                                           coef1, P1r, P1i);
    // 4) conv2 + store + stats partials (COG=5 -> grid.y = 4)
    k_conv2_stats<<<dim3(NB2, C2c / COG), 256, 0, stream>>>(P1r, P1i, w2r, w2i, b2r, b2i,
                                                            buf2r, buf2i, part2);
    k_part_reduce<<<C2c, 320, 0, stream>>>(part2, NB2, sums2);
    // 5) BN2 coefs
    k_bn_coef<<<1, 64, 0, stream>>>(sums2, C2c, 1.0 / ((double)BB * OH2 * OW2),
                                    g2rr, g2ri, g2ii, be2r, be2i, coef2);
    // 6) BN2 + relu + pool -> P2T [26000][64]
    k_bn2_pool<<<6500, 256, 0, stream>>>(buf2r, buf2i, coef2, P2Tr, P2Ti);
    // 7) FC1 GEMM (K=26000, 813 stages, split 64)
    k_gemm_cplx<<<dim3(8, 64), 256, 0, stream>>>(P2Tr, P2Ti, f1wr, f1wi, fc1r, fc1i,
                                                 FLAT, 813, 64);
    // 8) BN3 coefs
    k_bnfc_coef<<<2, 256, 0, stream>>>(fc1r, fc1i, HID, g3rr, g3ri, g3ii, be3r, be3i, coefF1);
    // 9) BN3 apply + relu -> transposed [512][64]
    k_bnfc_apply<<<128, 256, 0, stream>>>(fc1r, fc1i, coefF1, fc1aTr, fc1aTi, HID, 1);
    // 10) FC2 GEMM (K=512, 16 stages, split 16)
    k_gemm_cplx<<<dim3(8, 16), 256, 0, stream>>>(fc1aTr, fc1aTi, f2wr, f2wi, fc2r, fc2i,
                                                 HID, 16, 16);
    // 11) BN4 coefs
    k_bnfc_coef<<<2, 256, 0, stream>>>(fc2r, fc2i, HID, g4rr, g4ri, g4ii, be4r, be4i, coefF2);
    // 12) BN4 apply + relu -> [64][512]
    k_bnfc_apply<<<128, 256, 0, stream>>>(fc2r, fc2i, coefF2, fc2ar, fc2ai, HID, 0);
    // 13) classifier + log_softmax
    k_classifier<<<64, 64, 0, stream>>>(fc2ar, fc2ai, cwr, cwi, cbr, cbi, out);
}

// Round 5
// 873.042 us; speedup vs baseline: 1.1911x; 1.1911x over previous
//
#include <hip/hip_runtime.h>
#include <math.h>

// ---------------- dims ----------------
#define BB 64
#define H1 116
#define W1 212
#define C1c 10
#define OH1 112
#define OW1 208
#define PH1 56
#define PW1 104
#define C2c 20
#define OH2 52
#define OW2 100
#define PH2 26
#define PW2 50
#define FLAT 26000
#define HID 512
#define NCLS 10
#define EPSV 1e-5
#define NB1 1456
#define NB2 325
#define COG 2   // conv2 output channels per thread (grid.y = C2c/COG = 10)
                // COG=5 blew VGPR to 244 (occ 10%, 474us); COG=1 was 68 VGPR
                // but 5x input re-fetch (362us). COG=2: acc=16 regs, 2x amortize.

// ============================================================
// init: bias-init FC accumulators
// ============================================================
__global__ __launch_bounds__(256) void k_init(
                       float* fc1r, float* fc1i, float* fc2r, float* fc2i,
                       const float* __restrict__ f1br, const float* __restrict__ f1bi,
                       const float* __restrict__ f2br, const float* __restrict__ f2bi) {
    int idx = blockIdx.x * 256 + threadIdx.x;
    if (idx < BB * HID) {
        int n = idx % HID;
        fc1r[idx] = f1br[n]; fc1i[idx] = f1bi[n];
        fc2r[idx] = f2br[n]; fc2i[idx] = f2bi[n];
    }
}

// ============================================================
// conv1 + stats partials (no store; conv1 recomputed in apply pass)
// grid (1456, 10), block 256.
// ============================================================
__global__ __launch_bounds__(256) void k_conv1_stats(
                              const float* __restrict__ xr, const float* __restrict__ xi,
                              const float* __restrict__ w1r, const float* __restrict__ w1i,
                              const float* __restrict__ b1r, const float* __restrict__ b1i,
                              double* __restrict__ part) {
    __shared__ float swr[25], swi[25];
    __shared__ double red[4][5];
    int tid = threadIdx.x;
    int c = blockIdx.y;
    if (tid < 25) { swr[tid] = w1r[c * 25 + tid]; swi[tid] = w1i[c * 25 + tid]; }
    __syncthreads();
    int idx = blockIdx.x * 256 + tid;
    int wg = idx % 52;
    int h  = (idx / 52) % OH1;
    int b  = idx / (52 * OH1);
    int w0 = wg * 4;
    float br = b1r[c], bi = b1i[c];
    float yr[4], yi[4];
#pragma unroll
    for (int j = 0; j < 4; j++) { yr[j] = br; yi[j] = bi; }
    const float* xrb = xr + b * (H1 * W1);
    const float* xib = xi + b * (H1 * W1);
#pragma unroll
    for (int kh = 0; kh < 5; kh++) {
        float ar[8], ai[8];
        const float* pr = xrb + (h + kh) * W1 + w0;
        const float* pi = xib + (h + kh) * W1 + w0;
        *(float4*)&ar[0] = *(const float4*)pr;
        *(float4*)&ar[4] = *(const float4*)(pr + 4);
        *(float4*)&ai[0] = *(const float4*)pi;
        *(float4*)&ai[4] = *(const float4*)(pi + 4);
#pragma unroll
        for (int kw = 0; kw < 5; kw++) {
            float wrv = swr[kh * 5 + kw], wiv = swi[kh * 5 + kw];
#pragma unroll
            for (int j = 0; j < 4; j++) {
                float vr = ar[kw + j], vi = ai[kw + j];
                yr[j] += vr * wrv - vi * wiv;
                yi[j] += vr * wiv + vi * wrv;
            }
        }
    }
    double v[5] = {0, 0, 0, 0, 0};
#pragma unroll
    for (int j = 0; j < 4; j++) {
        double r = yr[j], i = yi[j];
        v[0] += r; v[1] += i; v[2] += r * r; v[3] += i * i; v[4] += r * i;
    }
#pragma unroll
    for (int m = 32; m >= 1; m >>= 1) {
#pragma unroll
        for (int q = 0; q < 5; q++) v[q] += __shfl_xor(v[q], m, 64);
    }
    if ((tid & 63) == 0) {
#pragma unroll
        for (int q = 0; q < 5; q++) red[tid >> 6][q] = v[q];
    }
    __syncthreads();
    if (tid == 0) {
#pragma unroll
        for (int q = 0; q < 5; q++)
            part[(c * 5 + q) * NB1 + blockIdx.x] = red[0][q] + red[1][q] + red[2][q] + red[3][q];
    }
}

// ============================================================
// reduce per-block partials -> sums[c*5+q]
// ============================================================
__global__ __launch_bounds__(320) void k_part_reduce(
                              const double* __restrict__ part, int NB,
                              double* __restrict__ sums) {
    int c = blockIdx.x;
    int q = threadIdx.x >> 6;
    int lane = threadIdx.x & 63;
    double s = 0.0;
    for (int b = lane; b < NB; b += 64) s += part[(c * 5 + q) * NB + b];
#pragma unroll
    for (int m = 32; m >= 1; m >>= 1) s += __shfl_xor(s, m, 64);
    if (lane == 0) sums[c * 5 + q] = s;
}

// ============================================================
// BN coefficients from double sums (conv layers)
// ============================================================
__global__ __launch_bounds__(64) void k_bn_coef(
                          const double* __restrict__ sums, int C, double invN,
                          const float* __restrict__ grr, const float* __restrict__ gri,
                          const float* __restrict__ gii,
                          const float* __restrict__ ber, const float* __restrict__ bei,
                          float* __restrict__ coef) {
    int c = threadIdx.x;
    if (c >= C) return;
    double sr = sums[c * 5 + 0], si = sums[c * 5 + 1];
    double srr = sums[c * 5 + 2], sii = sums[c * 5 + 3], sri = sums[c * 5 + 4];
    double mr = sr * invN, mi = si * invN;
    double Vrr = srr * invN - mr * mr + EPSV;
    double Vii = sii * invN - mi * mi + EPSV;
    double Vri = sri * invN - mr * mi;
    double s = sqrt(Vrr * Vii - Vri * Vri);
    double t = sqrt(Vrr + Vii + 2.0 * s);
    double inv = 1.0 / (s * t);
    double Rrr = (Vii + s) * inv, Rii = (Vrr + s) * inv, Rri = -Vri * inv;
    double Grr = grr[c], Gri = gri[c], Gii = gii[c];
    double Arr = Grr * Rrr + Gri * Rri, Ari = Grr * Rri + Gri * Rii;
    double Air = Gri * Rrr + Gii * Rri, Aii = Gri * Rri + Gii * Rii;
    coef[c * 6 + 0] = (float)Arr;
    coef[c * 6 + 1] = (float)Ari;
    coef[c * 6 + 2] = (float)Air;
    coef[c * 6 + 3] = (float)Aii;
    coef[c * 6 + 4] = (float)((double)ber[c] - (Arr * mr + Ari * mi));
    coef[c * 6 + 5] = (float)((double)bei[c] - (Air * mr + Aii * mi));
}

// ============================================================
// conv1 recompute + BN affine + relu + mag-pool -> P1 [b][c][56][104]
// grid (728, 10)
// ============================================================
__global__ __launch_bounds__(256) void k_conv1_apply_pool(
                                   const float* __restrict__ xr, const float* __restrict__ xi,
                                   const float* __restrict__ w1r, const float* __restrict__ w1i,
                                   const float* __restrict__ b1r, const float* __restrict__ b1i,
                                   const float* __restrict__ coef,
                                   float* __restrict__ P1r, float* __restrict__ P1i) {
    __shared__ float swr[25], swi[25];
    int tid = threadIdx.x;
    int c = blockIdx.y;
    if (tid < 25) { swr[tid] = w1r[c * 25 + tid]; swi[tid] = w1i[c * 25 + tid]; }
    __syncthreads();
    int idx = blockIdx.x * 256 + tid;
    int pwg = idx % 52;
    int ph  = (idx / 52) % PH1;
    int b   = idx / (52 * PH1);
    int h0 = 2 * ph, w0 = 4 * pwg;
    float br = b1r[c], bi = b1i[c];
    float yr[2][4], yi[2][4];
#pragma unroll
    for (int oi = 0; oi < 2; oi++)
#pragma unroll
        for (int j = 0; j < 4; j++) { yr[oi][j] = br; yi[oi][j] = bi; }
    const float* xrb = xr + b * (H1 * W1);
    const float* xib = xi + b * (H1 * W1);
#pragma unroll
    for (int r = 0; r < 6; r++) {
        float ar[8], ai[8];
        const float* pr = xrb + (h0 + r) * W1 + w0;
        const float* pi = xib + (h0 + r) * W1 + w0;
        *(float4*)&ar[0] = *(const float4*)pr;
        *(float4*)&ar[4] = *(const float4*)(pr + 4);
        *(float4*)&ai[0] = *(const float4*)pi;
        *(float4*)&ai[4] = *(const float4*)(pi + 4);
#pragma unroll
        for (int oi = 0; oi < 2; oi++) {
            int kh = r - oi;
            if (kh >= 0 && kh < 5) {
#pragma unroll
                for (int kw = 0; kw < 5; kw++) {
                    float wrv = swr[kh * 5 + kw], wiv = swi[kh * 5 + kw];
#pragma unroll
                    for (int j = 0; j < 4; j++) {
                        float vr = ar[kw + j], vi = ai[kw + j];
                        yr[oi][j] += vr * wrv - vi * wiv;
                        yi[oi][j] += vr * wiv + vi * wrv;
                    }
                }
            }
        }
    }
    float Arr = coef[c * 6 + 0], Ari = coef[c * 6 + 1];
    float Air = coef[c * 6 + 2], Aii = coef[c * 6 + 3];
    float oR = coef[c * 6 + 4], oI = coef[c * 6 + 5];
    float bm0 = -1.f, br0 = 0.f, bi0 = 0.f;
    float bm1 = -1.f, br1 = 0.f, bi1 = 0.f;
#pragma unroll
    for (int oi = 0; oi < 2; oi++) {
#pragma unroll
        for (int j = 0; j < 4; j++) {
            float rr = fmaxf(Arr * yr[oi][j] + Ari * yi[oi][j] + oR, 0.f);
            float ii = fmaxf(Air * yr[oi][j] + Aii * yi[oi][j] + oI, 0.f);
            float m = rr * rr + ii * ii;
            if (j < 2) { if (m > bm0) { bm0 = m; br0 = rr; bi0 = ii; } }
            else       { if (m > bm1) { bm1 = m; br1 = rr; bi1 = ii; } }
        }
    }
    int pbase = ((b * C1c + c) * PH1 + ph) * PW1 + 2 * pwg;
    *(float2*)&P1r[pbase] = make_float2(br0, br1);
    *(float2*)&P1i[pbase] = make_float2(bi0, bi1);
}

// ============================================================
// conv2: P1 -> buf2 [b][c][52][100] (stored) + stats partials
// grid (325, 10): COG=2 output channels/thread, 4 pixels/thread.
// ============================================================
__global__ __launch_bounds__(256) void k_conv2_stats(
                              const float* __restrict__ P1r, const float* __restrict__ P1i,
                              const float* __restrict__ w2r, const float* __restrict__ w2i,
                              const float* __restrict__ b2r, const float* __restrict__ b2i,
                              float* __restrict__ buf2r, float* __restrict__ buf2i,
                              double* __restrict__ part) {
    __shared__ float swr[COG][250], swi[COG][250];
    __shared__ double red[4][5];
    int tid = threadIdx.x;
    int cg = blockIdx.y;                 // channel group: couts cg*COG .. cg*COG+COG-1
    if (tid < 250) {
#pragma unroll
        for (int g = 0; g < COG; g++) {
            swr[g][tid] = w2r[(cg * COG + g) * 250 + tid];
            swi[g][tid] = w2i[(cg * COG + g) * 250 + tid];
        }
    }
    __syncthreads();
    int idx = blockIdx.x * 256 + tid;
    int wg = idx % 25;
    int h  = (idx / 25) % OH2;
    int b  = idx / (25 * OH2);
    int w0 = 4 * wg;
    float yr[COG][4], yi[COG][4];
#pragma unroll
    for (int g = 0; g < COG; g++) {
        float br = b2r[cg * COG + g], bi = b2i[cg * COG + g];
#pragma unroll
        for (int j = 0; j < 4; j++) { yr[g][j] = br; yi[g][j] = bi; }
    }
    for (int cin = 0; cin < C1c; cin++) {
        const float* pr = P1r + ((b * C1c + cin) * PH1 + h) * PW1 + w0;
        const float* pi = P1i + ((b * C1c + cin) * PH1 + h) * PW1 + w0;
#pragma unroll
        for (int kh = 0; kh < 5; kh++) {
            float ar[8], ai[8];
            *(float4*)&ar[0] = *(const float4*)(pr + kh * PW1);
            *(float4*)&ar[4] = *(const float4*)(pr + kh * PW1 + 4);
            *(float4*)&ai[0] = *(const float4*)(pi + kh * PW1);
            *(float4*)&ai[4] = *(const float4*)(pi + kh * PW1 + 4);
#pragma unroll
            for (int g = 0; g < COG; g++) {
                const float* wr = &swr[g][cin * 25 + kh * 5];
                const float* wi = &swi[g][cin * 25 + kh * 5];
#pragma unroll
                for (int kw = 0; kw < 5; kw++) {
                    float wrv = wr[kw], wiv = wi[kw];
#pragma unroll
                    for (int j = 0; j < 4; j++) {
                        float vr = ar[kw + j], vi = ai[kw + j];
                        yr[g][j] += vr * wrv - vi * wiv;
                        yi[g][j] += vr * wiv + vi * wrv;
                    }
                }
            }
        }
    }
#pragma unroll
    for (int g = 0; g < COG; g++) {
        int ob = ((b * C2c + cg * COG + g) * OH2 + h) * OW2 + w0;
        *(float4*)&buf2r[ob] = make_float4(yr[g][0], yr[g][1], yr[g][2], yr[g][3]);
        *(float4*)&buf2i[ob] = make_float4(yi[g][0], yi[g][1], yi[g][2], yi[g][3]);
    }
    // stats: sequential per channel to cap register pressure
    for (int g = 0; g < COG; g++) {
        double v[5] = {0, 0, 0, 0, 0};
#pragma unroll
        for (int j = 0; j < 4; j++) {
            double r = yr[g][j], i = yi[g][j];
            v[0] += r; v[1] += i; v[2] += r * r; v[3] += i * i; v[4] += r * i;
        }
#pragma unroll
        for (int m = 32; m >= 1; m >>= 1) {
#pragma unroll
            for (int q = 0; q < 5; q++) v[q] += __shfl_xor(v[q], m, 64);
        }
        if ((tid & 63) == 0) {
#pragma unroll
            for (int q = 0; q < 5; q++) red[tid >> 6][q] = v[q];
        }
        __syncthreads();
        if (tid == 0) {
            int c = cg * COG + g;
#pragma unroll
            for (int q = 0; q < 5; q++)
                part[(c * 5 + q) * NB2 + blockIdx.x] = red[0][q] + red[1][q] + red[2][q] + red[3][q];
        }
        __syncthreads();
    }
}

// ============================================================
// BN2 affine + relu + mag-pool, write transposed P2T [k=26000][b=64]
// ============================================================
__global__ __launch_bounds__(256) void k_bn2_pool(
                           const float* __restrict__ buf2r, const float* __restrict__ buf2i,
                           const float* __restrict__ coef,
                           float* __restrict__ P2Tr, float* __restrict__ P2Ti) {
    int idx = blockIdx.x * 256 + threadIdx.x;
    int pw = idx % PW2;
    int ph = (idx / PW2) % PH2;
    int c  = (idx / (PW2 * PH2)) % C2c;
    int b  = idx / (PW2 * PH2 * C2c);
    float Arr = coef[c * 6 + 0], Ari = coef[c * 6 + 1];
    float Air = coef[c * 6 + 2], Aii = coef[c * 6 + 3];
    float oR = coef[c * 6 + 4], oI = coef[c * 6 + 5];
    int ib = ((b * C2c + c) * OH2 + 2 * ph) * OW2 + 2 * pw;
    float rv[4], iv[4];
    rv[0] = buf2r[ib];           iv[0] = buf2i[ib];
    rv[1] = buf2r[ib + 1];       iv[1] = buf2i[ib + 1];
    rv[2] = buf2r[ib + OW2];     iv[2] = buf2i[ib + OW2];
    rv[3] = buf2r[ib + OW2 + 1]; iv[3] = buf2i[ib + OW2 + 1];
    float bm = -1.f, brv = 0.f, biv = 0.f;
#pragma unroll
    for (int q = 0; q < 4; q++) {
        float rr = fmaxf(Arr * rv[q] + Ari * iv[q] + oR, 0.f);
        float ii = fmaxf(Air * rv[q] + Aii * iv[q] + oI, 0.f);
        float m = rr * rr + ii * ii;
        if (m > bm) { bm = m; brv = rr; biv = ii; }
    }
    int k = (c * PH2 + ph) * PW2 + pw;
    P2Tr[k * BB + b] = brv;
    P2Ti[k * BB + b] = biv;
}

// ============================================================
// complex GEMM: out[64][512] += XT[k][64] (x) W[n][k]
// ============================================================
#define GKC 32
__global__ __launch_bounds__(256) void k_gemm_cplx(
                            const float* __restrict__ XTr, const float* __restrict__ XTi,
                            const float* __restrict__ Wr, const float* __restrict__ Wi,
                            float* __restrict__ outR, float* __restrict__ outI,
                            int K, int nStages, int nSplit) {
    __shared__ float lxr[GKC][64], lxi[GKC][64];
    __shared__ float lwr[GKC][68], lwi[GKC][68];
    int tid = threadIdx.x;
    int n0 = blockIdx.x * 64;
    int split = blockIdx.y;
    int bq = tid & 15, nq = tid >> 4;
    int nl = tid & 63, kg = tid >> 6;
    float accR[4][4] = {}, accI[4][4] = {};
    for (int st = split; st < nStages; st += nSplit) {
        int k0 = st * GKC;
        __syncthreads();
#pragma unroll
        for (int u = 0; u < 2; u++) {
            int p = u * 1024 + tid * 4;
            int g = k0 * 64 + p;
            float4 vr = make_float4(0.f, 0.f, 0.f, 0.f), vi = vr;
            if (g < K * 64) {
                vr = *(const float4*)(XTr + g);
                vi = *(const float4*)(XTi + g);
            }
            *(float4*)&((float*)lxr)[p] = vr;
            *(float4*)&((float*)lxi)[p] = vi;
        }
#pragma unroll
        for (int u = 0; u < 2; u++) {
            int koff = kg * 8 + u * 4;
            int k = k0 + koff;
            float4 vr = make_float4(0.f, 0.f, 0.f, 0.f), vi = vr;
            if (k < K) {
                vr = *(const float4*)(Wr + (size_t)(n0 + nl) * K + k);
                vi = *(const float4*)(Wi + (size_t)(n0 + nl) * K + k);
            }
            lwr[koff + 0][nl] = vr.x; lwr[koff + 1][nl] = vr.y;
            lwr[koff + 2][nl] = vr.z; lwr[koff + 3][nl] = vr.w;
            lwi[koff + 0][nl] = vi.x; lwi[koff + 1][nl] = vi.y;
            lwi[koff + 2][nl] = vi.z; lwi[koff + 3][nl] = vi.w;
        }
        __syncthreads();
#pragma unroll 4
        for (int kk = 0; kk < GKC; kk++) {
            float4 xr4 = *(const float4*)&lxr[kk][bq * 4];
            float4 xi4 = *(const float4*)&lxi[kk][bq * 4];
            float4 wr4 = *(const float4*)&lwr[kk][nq * 4];
            float4 wi4 = *(const float4*)&lwi[kk][nq * 4];
            float xra[4] = {xr4.x, xr4.y, xr4.z, xr4.w};
            float xia[4] = {xi4.x, xi4.y, xi4.z, xi4.w};
            float wra[4] = {wr4.x, wr4.y, wr4.z, wr4.w};
            float wia[4] = {wi4.x, wi4.y, wi4.z, wi4.w};
#pragma unroll
            for (int i = 0; i < 4; i++)
#pragma unroll
                for (int j = 0; j < 4; j++) {
                    accR[i][j] += xra[i] * wra[j] - xia[i] * wia[j];
                    accI[i][j] += xra[i] * wia[j] + xia[i] * wra[j];
                }
        }
    }
#pragma unroll
    for (int i = 0; i < 4; i++)
#pragma unroll
        for (int j = 0; j < 4; j++) {
            int b = bq * 4 + i;
            int n = n0 + nq * 4 + j;
            unsafeAtomicAdd(&outR[b * HID + n], accR[i][j]);
            unsafeAtomicAdd(&outI[b * HID + n], accI[i][j]);
        }
}

// ============================================================
// FC BN coef (batch axis only, N=64), C features
// ============================================================
__global__ __launch_bounds__(256) void k_bnfc_coef(
                            const float* __restrict__ inr, const float* __restrict__ ini, int C,
                            const float* __restrict__ grr, const float* __restrict__ gri,
                            const float* __restrict__ gii,
                            const float* __restrict__ ber, const float* __restrict__ bei,
                            float* __restrict__ coef) {
    int f = blockIdx.x * 256 + threadIdx.x;
    if (f >= C) return;
    double sr = 0, si = 0, srr = 0, sii = 0, sri = 0;
    for (int b = 0; b < BB; b++) {
        double r = inr[b * C + f], i = ini[b * C + f];
        sr += r; si += i; srr += r * r; sii += i * i; sri += r * i;
    }
    double invN = 1.0 / BB;
    double mr = sr * invN, mi = si * invN;
    double Vrr = srr * invN - mr * mr + EPSV;
    double Vii = sii * invN - mi * mi + EPSV;
    double Vri = sri * invN - mr * mi;
    double s = sqrt(Vrr * Vii - Vri * Vri);
    double t = sqrt(Vrr + Vii + 2.0 * s);
    double inv = 1.0 / (s * t);
    double Rrr = (Vii + s) * inv, Rii = (Vrr + s) * inv, Rri = -Vri * inv;
    double Grr = grr[f], Gri = gri[f], Gii = gii[f];
    double Arr = Grr * Rrr + Gri * Rri, Ari = Grr * Rri + Gri * Rii;
    double Air = Gri * Rrr + Gii * Rri, Aii = Gri * Rri + Gii * Rii;
    coef[f * 6 + 0] = (float)Arr;
    coef[f * 6 + 1] = (float)Ari;
    coef[f * 6 + 2] = (float)Air;
    coef[f * 6 + 3] = (float)Aii;
    coef[f * 6 + 4] = (float)((double)ber[f] - (Arr * mr + Ari * mi));
    coef[f * 6 + 5] = (float)((double)bei[f] - (Air * mr + Aii * mi));
}

// ============================================================
// FC BN apply + relu; optional transposed output [f][64]
// ============================================================
__global__ __launch_bounds__(256) void k_bnfc_apply(
                             const float* __restrict__ inr, const float* __restrict__ ini,
                             const float* __restrict__ coef,
                             float* __restrict__ outr, float* __restrict__ outi,
                             int C, int transposeOut) {
    int idx = blockIdx.x * 256 + threadIdx.x;
    if (idx >= BB * C) return;
    int f = idx % C;
    int b = idx / C;
    float r = inr[idx], i = ini[idx];
    float rr = fmaxf(coef[f * 6 + 0] * r + coef[f * 6 + 1] * i + coef[f * 6 + 4], 0.f);
    float ii = fmaxf(coef[f * 6 + 2] * r + coef[f * 6 + 3] * i + coef[f * 6 + 5], 0.f);
    if (transposeOut) { outr[f * BB + b] = rr; outi[f * BB + b] = ii; }
    else              { outr[idx] = rr;        outi[idx] = ii; }
}

// ============================================================
// classifier (512->10 complex) + |z|^2 + log_softmax
// ============================================================
__global__ __launch_bounds__(64) void k_classifier(
                             const float* __restrict__ xr, const float* __restrict__ xi,
                             const float* __restrict__ cwr, const float* __restrict__ cwi,
                             const float* __restrict__ cbr, const float* __restrict__ cbi,
                             float* __restrict__ out) {
    int b = blockIdx.x;
    int lane = threadIdx.x;
    __shared__ float z[NCLS];
    for (int cls = 0; cls < NCLS; cls++) {
        float ar = 0.f, ai = 0.f;
#pragma unroll
        for (int j = 0; j < 8; j++) {
            int k = j * 64 + lane;
            float xrv = xr[b * HID + k], xiv = xi[b * HID + k];
            float wr = cwr[cls * HID + k], wi = cwi[cls * HID + k];
            ar += xrv * wr - xiv * wi;
            ai += xrv * wi + xiv * wr;
        }
#pragma unroll
        for (int m = 32; m >= 1; m >>= 1) {
            ar += __shfl_xor(ar, m, 64);
            ai += __shfl_xor(ai, m, 64);
        }
        if (lane == 0) {
            float hr = ar + cbr[cls], hi = ai + cbi[cls];
            z[cls] = hr * hr + hi * hi;
        }
    }
    __syncthreads();
    if (lane == 0) {
        float mx = z[0];
#pragma unroll
        for (int c = 1; c < NCLS; c++) mx = fmaxf(mx, z[c]);
        float s = 0.f;
#pragma unroll
        for (int c = 0; c < NCLS; c++) s += expf(z[c] - mx);
        float ls = logf(s);
#pragma unroll
        for (int c = 0; c < NCLS; c++) out[b * NCLS + c] = z[c] - mx - ls;
    }
}

// ============================================================
extern "C" void kernel_launch(void* const* d_in, const int* in_sizes, int n_in,
                              void* d_out, int out_size, void* d_ws, size_t ws_size,
                              hipStream_t stream) {
    const float* x_re = (const float*)d_in[0];
    const float* x_im = (const float*)d_in[1];
    const float* w1r = (const float*)d_in[2];
    const float* w1i = (const float*)d_in[3];
    const float* b1r = (const float*)d_in[4];
    const float* b1i = (const float*)d_in[5];
    const float* g1rr = (const float*)d_in[6];
    const float* g1ri = (const float*)d_in[7];
    const float* g1ii = (const float*)d_in[8];
    const float* be1r = (const float*)d_in[9];
    const float* be1i = (const float*)d_in[10];
    const float* w2r = (const float*)d_in[11];
    const float* w2i = (const float*)d_in[12];
    const float* b2r = (const float*)d_in[13];
    const float* b2i = (const float*)d_in[14];
    const float* g2rr = (const float*)d_in[15];
    const float* g2ri = (const float*)d_in[16];
    const float* g2ii = (const float*)d_in[17];
    const float* be2r = (const float*)d_in[18];
    const float* be2i = (const float*)d_in[19];
    const float* f1wr = (const float*)d_in[20];
    const float* f1wi = (const float*)d_in[21];
    const float* f1br = (const float*)d_in[22];
    const float* f1bi = (const float*)d_in[23];
    const float* g3rr = (const float*)d_in[24];
    const float* g3ri = (const float*)d_in[25];
    const float* g3ii = (const float*)d_in[26];
    const float* be3r = (const float*)d_in[27];
    const float* be3i = (const float*)d_in[28];
    const float* f2wr = (const float*)d_in[29];
    const float* f2wi = (const float*)d_in[30];
    const float* f2br = (const float*)d_in[31];
    const float* f2bi = (const float*)d_in[32];
    const float* g4rr = (const float*)d_in[33];
    const float* g4ri = (const float*)d_in[34];
    const float* g4ii = (const float*)d_in[35];
    const float* be4r = (const float*)d_in[36];
    const float* be4i = (const float*)d_in[37];
    const float* cwr = (const float*)d_in[38];
    const float* cwi = (const float*)d_in[39];
    const float* cbr = (const float*)d_in[40];
    const float* cbi = (const float*)d_in[41];
    float* out = (float*)d_out;

    char* ws = (char*)d_ws;
    size_t off = 0;
    auto alloc = [&](size_t nbytes) -> void* {
        off = (off + 255) & ~(size_t)255;
        void* p = ws + off;
        off += nbytes;
        return p;
    };
    float* P1r   = (float*)alloc((size_t)BB * C1c * PH1 * PW1 * 4);
    float* P1i   = (float*)alloc((size_t)BB * C1c * PH1 * PW1 * 4);
    float* buf2r = (float*)alloc((size_t)BB * C2c * OH2 * OW2 * 4);
    float* buf2i = (float*)alloc((size_t)BB * C2c * OH2 * OW2 * 4);
    float* P2Tr  = (float*)alloc((size_t)FLAT * BB * 4);
    float* P2Ti  = (float*)alloc((size_t)FLAT * BB * 4);
    float* fc1r  = (float*)alloc((size_t)BB * HID * 4);
    float* fc1i  = (float*)alloc((size_t)BB * HID * 4);
    float* fc1aTr = (float*)alloc((size_t)HID * BB * 4);
    float* fc1aTi = (float*)alloc((size_t)HID * BB * 4);
    float* fc2r  = (float*)alloc((size_t)BB * HID * 4);
    float* fc2i  = (float*)alloc((size_t)BB * HID * 4);
    float* fc2ar = (float*)alloc((size_t)BB * HID * 4);
    float* fc2ai = (float*)alloc((size_t)BB * HID * 4);
    double* part1 = (double*)alloc((size_t)C1c * 5 * NB1 * 8);
    double* part2 = (double*)alloc((size_t)C2c * 5 * NB2 * 8);
    double* sums1 = (double*)alloc(C1c * 5 * 8);
    double* sums2 = (double*)alloc(C2c * 5 * 8);
    float* coef1 = (float*)alloc(C1c * 6 * 4);
    float* coef2 = (float*)alloc(C2c * 6 * 4);
    float* coefF1 = (float*)alloc(HID * 6 * 4);
    float* coefF2 = (float*)alloc(HID * 6 * 4);

    // 0) init
    k_init<<<128, 256, 0, stream>>>(fc1r, fc1i, fc2r, fc2i, f1br, f1bi, f2br, f2bi);
    // 1) conv1 stats partials
    k_conv1_stats<<<dim3(NB1, C1c), 256, 0, stream>>>(x_re, x_im, w1r, w1i, b1r, b1i, part1);
    k_part_reduce<<<C1c, 320, 0, stream>>>(part1, NB1, sums1);
    // 2) BN1 coefs
    k_bn_coef<<<1, 64, 0, stream>>>(sums1, C1c, 1.0 / ((double)BB * OH1 * OW1),
                                    g1rr, g1ri, g1ii, be1r, be1i, coef1);
    // 3) conv1 + BN + relu + pool -> P1
    k_conv1_apply_pool<<<dim3(728, C1c), 256, 0, stream>>>(x_re, x_im, w1r, w1i, b1r, b1i,
                                                           coef1, P1r, P1i);
    // 4) conv2 + store + stats partials (COG=2 -> grid.y = 10)
    k_conv2_stats<<<dim3(NB2, C2c / COG), 256, 0, stream>>>(P1r, P1i, w2r, w2i, b2r, b2i,
                                                            buf2r, buf2i, part2);
    k_part_reduce<<<C2c, 320, 0, stream>>>(part2, NB2, sums2);
    // 5) BN2 coefs
    k_bn_coef<<<1, 64, 0, stream>>>(sums2, C2c, 1.0 / ((double)BB * OH2 * OW2),
                                    g2rr, g2ri, g2ii, be2r, be2i, coef2);
    // 6) BN2 + relu + pool -> P2T [26000][64]
    k_bn2_pool<<<6500, 256, 0, stream>>>(buf2r, buf2i, coef2, P2Tr, P2Ti);
    // 7) FC1 GEMM (K=26000, 813 stages, split 64)
    k_gemm_cplx<<<dim3(8, 64), 256, 0, stream>>>(P2Tr, P2Ti, f1wr, f1wi, fc1r, fc1i,
                                                 FLAT, 813, 64);
    // 8) BN3 coefs
    k_bnfc_coef<<<2, 256, 0, stream>>>(fc1r, fc1i, HID, g3rr, g3ri, g3ii, be3r, be3i, coefF1);
    // 9) BN3 apply + relu -> transposed [512][64]
    k_bnfc_apply<<<128, 256, 0, stream>>>(fc1r, fc1i, coefF1, fc1aTr, fc1aTi, HID, 1);
    // 10) FC2 GEMM (K=512, 16 stages, split 16)
    k_gemm_cplx<<<dim3(8, 16), 256, 0, stream>>>(fc1aTr, fc1aTi, f2wr, f2wi, fc2r, fc2i,
                                                 HID, 16, 16);
    // 11) BN4 coefs
    k_bnfc_coef<<<2, 256, 0, stream>>>(fc2r, fc2i, HID, g4rr, g4ri, g4ii, be4r, be4i, coefF2);
    // 12) BN4 apply + relu -> [64][512]
    k_bnfc_apply<<<128, 256, 0, stream>>>(fc2r, fc2i, coefF2, fc2ar, fc2ai, HID, 0);
    // 13) classifier + log_softmax
    k_classifier<<<64, 64, 0, stream>>>(fc2ar, fc2ai, cwr, cwi, cbr, cbi, out);
}